// Round 5
// baseline (2381.480 us; speedup 1.0000x reference)
//
#include <hip/hip_runtime.h>

typedef unsigned short u16;
typedef unsigned int u32;

#define NTOK 144
#define CDIM 192
#define NHEADS 6
#define HDIM 32
#define NWIN 64
#define NB 30
#define NBLK (NB * NWIN)
#define TABLE_N 3312
#define SCALE 0.17677669529663687f

typedef __bf16 bf16x8 __attribute__((ext_vector_type(8)));
typedef u16 u16x8 __attribute__((ext_vector_type(8)));
typedef u16 u16x4 __attribute__((ext_vector_type(4)));
typedef float f32x4 __attribute__((ext_vector_type(4)));

__device__ __forceinline__ float bf2f(u16 u) {
    union { u32 i; float f; } v; v.i = ((u32)u) << 16; return v.f;
}
__device__ __forceinline__ u16 f2bf(float f) {
    union { float f; u32 i; } v; v.f = f;
    u32 r = v.i + 0x7FFFu + ((v.i >> 16) & 1u);   // RNE
    return (u16)(r >> 16);
}

// -------- dtype-robust accessors (fm==1: raw buffers are fp32) --------
__device__ __forceinline__ bf16x8 ld_frag(const void* base, size_t idx, int fm) {
    if (!fm) return *(const bf16x8*)((const u16*)base + idx);
    const float* pf = (const float*)base;
    u16x8 t;
#pragma unroll
    for (int j = 0; j < 8; ++j) t[j] = f2bf(pf[idx + j]);
    union { u16x8 u; bf16x8 b; } cv; cv.u = t; return cv.b;
}
__device__ __forceinline__ float ld_s(const void* base, size_t idx, int fm) {
    return fm ? ((const float*)base)[idx] : bf2f(((const u16*)base)[idx]);
}
__device__ __forceinline__ void st_s(void* base, size_t idx, float v, int fm) {
    if (fm) ((float*)base)[idx] = v; else ((u16*)base)[idx] = f2bf(v);
}
__device__ __forceinline__ bf16x8 zero_frag() {
    union { u16x8 u; bf16x8 b; } cv;
#pragma unroll
    for (int j = 0; j < 8; ++j) cv.u[j] = 0;
    return cv.b;
}
// x A-fragment loader (16B worth of bf16; converts when fm)
__device__ __forceinline__ bf16x8 ld_x_frag(const void* x, size_t rowbase, int off, int fm) {
    if (!fm) return *(const bf16x8*)((const u16*)x + rowbase + off);
    const float* xs = (const float*)x + rowbase + off;
    const float4 a0 = *(const float4*)xs;
    const float4 a1 = *(const float4*)(xs + 4);
    union { u16x8 u; bf16x8 b; } cv;
    cv.u[0] = f2bf(a0.x); cv.u[1] = f2bf(a0.y); cv.u[2] = f2bf(a0.z); cv.u[3] = f2bf(a0.w);
    cv.u[4] = f2bf(a1.x); cv.u[5] = f2bf(a1.y); cv.u[6] = f2bf(a1.z); cv.u[7] = f2bf(a1.w);
    return cv.b;
}

// -------- detector: bf16 vs fp32 input encoding --------
__global__ void detect_mode(const u16* __restrict__ w, int* __restrict__ flag) {
    __shared__ int cnt;
    if (threadIdx.x == 0) cnt = 0;
    __syncthreads();
    int h = 0;
    for (int i = threadIdx.x; i < 4096; i += 256) {
        int e = (w[i] >> 7) & 0xFF;
        if (e >= 0x8E) h++;
    }
    atomicAdd(&cnt, h);
    __syncthreads();
    if (threadIdx.x == 0) flag[0] = (cnt > 64) ? 1 : 0;
}

// -------- prologue: bias in MFMA FRAGMENT layout --------
// bias_f[w][h][T(9)][nt(9)][lane(64)][r(4)] bf16: per (T,nt) a lane reads its 4
// C-frag bias values as one contiguous 8B load.
__global__ void bias_gather3(const void* __restrict__ table, const int* __restrict__ pos,
                             u16* __restrict__ bias_f, const int* __restrict__ mode) {
    __shared__ u16 smT[TABLE_N];
    const int fm = mode[0];
    const int w = blockIdx.x / NHEADS, h = blockIdx.x % NHEADS;
    for (int t = threadIdx.x; t < TABLE_N; t += 256) {
        size_t j = (size_t)t * (NWIN * NHEADS) + w * NHEADS + h;
        smT[t] = fm ? f2bf(((const float*)table)[j]) : ((const u16*)table)[j];
    }
    __syncthreads();
    u16* o = bias_f + (size_t)(w * NHEADS + h) * (81 * 256);
    for (int i = threadIdx.x; i < 81 * 256; i += 256) {
        int T = i / 2304, rem2 = i % 2304;
        int nt = rem2 >> 8, lane = (rem2 >> 2) & 63, r = rem2 & 3;
        int row = T * 16 + (lane >> 4) * 4 + r;
        int col = nt * 16 + (lane & 15);
        o[i] = smT[pos[row * NTOK + col]];
    }
}

// -------- prologue: canonical bf16 weights in workspace (one-time) --------
__global__ void wconv(const void* __restrict__ qkv_w, const void* __restrict__ qkv_b,
                      const void* __restrict__ proj_w, const void* __restrict__ proj_b,
                      u16* __restrict__ qkvw_c, u16* __restrict__ projw_c,
                      u16* __restrict__ qkvb_c, u16* __restrict__ projb_c,
                      const int* __restrict__ mode) {
    const int fm = mode[0];
    const int gid = blockIdx.x * blockDim.x + threadIdx.x;
    const int np  = gridDim.x * blockDim.x;
    const int NQW = 3 * CDIM * CDIM, NPW = CDIM * CDIM;
    if (fm) {
        const float* a = (const float*)qkv_w;
        const float* b = (const float*)proj_w;
        const float* c = (const float*)qkv_b;
        const float* d = (const float*)proj_b;
        for (int i = gid; i < NQW; i += np) qkvw_c[i] = f2bf(a[i]);
        for (int i = gid; i < NPW; i += np) projw_c[i] = f2bf(b[i]);
        for (int i = gid; i < 3 * CDIM; i += np) qkvb_c[i] = f2bf(c[i]);
        for (int i = gid; i < CDIM; i += np) projb_c[i] = f2bf(d[i]);
    } else {
        const u16* a = (const u16*)qkv_w;
        const u16* b = (const u16*)proj_w;
        const u16* c = (const u16*)qkv_b;
        const u16* d = (const u16*)proj_b;
        for (int i = gid; i < NQW; i += np) qkvw_c[i] = a[i];
        for (int i = gid; i < NPW; i += np) projw_c[i] = b[i];
        for (int i = gid; i < 3 * CDIM; i += np) qkvb_c[i] = c[i];
        for (int i = gid; i < CDIM; i += np) projb_c[i] = d[i];
    }
}

// =================== 3-split kernel A: QKV projection GEMM ===================
// One block per window, 512 thr (8 waves); LDS = W head-slice only (38.4 KB ->
// up to 4 blocks/CU). Writes q (pre-scaled) / k / v as bf16 [bw][h][144][32].
#define GW_STR 200
__global__ __launch_bounds__(512, 8)
void qkv_gemm(const void* __restrict__ x,
              const u16* __restrict__ qkvw_c, const u16* __restrict__ qkvb_c,
              u16* __restrict__ q_ws, u16* __restrict__ k_ws, u16* __restrict__ v_ws,
              const int* __restrict__ mode) {
    __shared__ __align__(16) u16 smW[96 * GW_STR];   // 38,400 B

    const int fm   = mode[0];
    const int tid  = threadIdx.x;
    const int wv   = tid >> 6;       // 0..7
    const int lane = tid & 63;
    const int l15  = lane & 15;
    const int lq   = lane >> 4;

    const int blk   = blockIdx.x;                       // 0..1919
    const int virt  = (blk & 7) * (NBLK / 8) + (blk >> 3);
    const int w     = virt / NB;
    const int bwlin = (virt % NB) * NWIN + w;

    const f32x4 fzero = {0.f, 0.f, 0.f, 0.f};

    for (int h = 0; h < NHEADS; ++h) {
        const int hoff = h * HDIM;

        // stage W head-slice (96x192) -> LDS [96][200]
        for (int i = tid; i < 96 * CDIM / 8; i += 512) {      // 2304
            int r = i / 24, c8 = (i % 24) * 8;
            int grow = (r >> 5) * CDIM + hoff + (r & 31);
            *(uint4*)&smW[r * GW_STR + c8] = *(const uint4*)(qkvw_c + (size_t)grow * CDIM + c8);
        }
        __syncthreads();

        const size_t obase = ((size_t)bwlin * NHEADS + h) * (NTOK * HDIM);
        for (int t = wv; t < 9; t += 8) {                     // wave0 also does tile 8
            const size_t xrow = ((size_t)bwlin * NTOK + t * 16 + l15) * CDIM;
            f32x4 acc[6];
#pragma unroll
            for (int nt = 0; nt < 6; ++nt) acc[nt] = fzero;
#pragma unroll
            for (int kt = 0; kt < 6; ++kt) {
                bf16x8 xf = ld_x_frag(x, xrow, kt * 32 + lq * 8, fm);
#pragma unroll
                for (int nt = 0; nt < 6; ++nt) {
                    bf16x8 bb = *(const bf16x8*)&smW[(nt * 16 + l15) * GW_STR + kt * 32 + lq * 8];
                    acc[nt] = __builtin_amdgcn_mfma_f32_16x16x32_bf16(xf, bb, acc[nt], 0, 0, 0);
                }
            }
#pragma unroll
            for (int nt = 0; nt < 6; ++nt) {
                int col = nt * 16 + l15;         // 0..95
                int s = col >> 5, d = col & 31;
                float bias = bf2f(qkvb_c[s * CDIM + hoff + d]);
#pragma unroll
                for (int r = 0; r < 4; ++r) {
                    int row = t * 16 + lq * 4 + r;
                    float v = acc[nt][r] + bias;
                    size_t idx = obase + (size_t)row * HDIM + d;
                    if (s == 0)      q_ws[idx] = f2bf(v * SCALE);
                    else if (s == 1) k_ws[idx] = f2bf(v);
                    else             v_ws[idx] = f2bf(v);
                }
            }
        }
        __syncthreads();   // all reads of W done before restage
    }
}

// =================== 3-split kernel B: per-(window,head) attention ===================
// 11520 blocks, 512 thr (8 waves). ONE barrier per block (after K/vT staging).
// Each wave: QK^T -> +bias -> softmax (regs) -> P (private LDS slab, no barrier)
// -> PV -> O store. LDS: K[144][40]@0, vT[32][152]@5760, P[9][16][152]@10624.
#define BK_OFF  0
#define BK_STR  40
#define BVT_OFF 5760
#define BVT_STR 152
#define BP_OFF  10624
#define BP_TILE 2432     // 16*152
#define BSM_TOT 32512    // u16 = 65,024 B -> 2 blocks/CU

__global__ __launch_bounds__(512, 4)
void attn_bh(const u16* __restrict__ q_ws, const u16* __restrict__ k_ws,
             const u16* __restrict__ v_ws, const u16* __restrict__ bias_f,
             u16* __restrict__ o_ws) {
    __shared__ __align__(16) u16 sm[BSM_TOT];

    const int tid  = threadIdx.x;
    const int wv   = tid >> 6;       // 0..7
    const int lane = tid & 63;
    const int l15  = lane & 15;
    const int lq   = lane >> 4;

    // XCD-chunked; within chunk order (w, h, b) so bias_f slice is L2-hot
    const int blk  = blockIdx.x;                         // 0..11519
    const int virt = (blk & 7) * (NBLK * NHEADS / 8) + (blk >> 3);
    const int w    = virt / (NB * NHEADS);
    const int rem  = virt % (NB * NHEADS);
    const int h    = rem / NB;
    const int b    = rem % NB;
    const int bwlin = b * NWIN + w;

    const size_t kvbase = ((size_t)bwlin * NHEADS + h) * (NTOK * HDIM);

    // stage K [144][32] -> LDS [144][40]
    for (int i = tid; i < 576; i += 512) {
        int r = i >> 2, c8 = (i & 3) * 8;
        *(uint4*)&sm[BK_OFF + r * BK_STR + c8] = *(const uint4*)(k_ws + kvbase + (size_t)r * HDIM + c8);
    }
    // stage v [144][32] -> vT LDS [32][152] (transpose via scalar writes)
    for (int i = tid; i < 576; i += 512) {
        int m = i >> 2, c8 = (i & 3) * 8;
        u16x8 vv = *(const u16x8*)(v_ws + kvbase + (size_t)m * HDIM + c8);
#pragma unroll
        for (int j = 0; j < 8; ++j)
            sm[BVT_OFF + (c8 + j) * BVT_STR + m] = vv[j];
    }
    __syncthreads();                                     // the only barrier

    const f32x4 fzero = {0.f, 0.f, 0.f, 0.f};

    for (int t = wv; t < 9; t += 8) {                    // wave0 also does tile 8
        // ---- QK^T: a from global q (1 b128), b from K LDS ----
        f32x4 sacc[9];
        {
            bf16x8 a = *(const bf16x8*)(q_ws + kvbase + (size_t)(t * 16 + l15) * HDIM + lq * 8);
#pragma unroll
            for (int nt = 0; nt < 9; ++nt) {
                bf16x8 bb = *(const bf16x8*)&sm[BK_OFF + (nt * 16 + l15) * BK_STR + lq * 8];
                sacc[nt] = __builtin_amdgcn_mfma_f32_16x16x32_bf16(a, bb, fzero, 0, 0, 0);
            }
        }
        // ---- + bias (fragment-layout coalesced) ----
        {
            const u16* bf = bias_f + ((size_t)(w * NHEADS + h) * 81 + t * 9) * 256;
#pragma unroll
            for (int nt = 0; nt < 9; ++nt) {
                u16x4 pk = *(const u16x4*)&bf[nt * 256 + (lane << 2)];
#pragma unroll
                for (int r = 0; r < 4; ++r) sacc[nt][r] += bf2f(pk[r]);
            }
        }
        // ---- softmax (registers, 16-lane row groups) ----
#pragma unroll
        for (int r = 0; r < 4; ++r) {
            float m = -1e30f;
            for (int nt = 0; nt < 9; ++nt) m = fmaxf(m, sacc[nt][r]);
            for (int d = 1; d < 16; d <<= 1) m = fmaxf(m, __shfl_xor(m, d, 64));
            float s = 0.f;
            for (int nt = 0; nt < 9; ++nt) {
                float e = __expf(sacc[nt][r] - m);
                sacc[nt][r] = e; s += e;
            }
            for (int d = 1; d < 16; d <<= 1) s += __shfl_xor(s, d, 64);
            float inv = 1.0f / s;
            for (int nt = 0; nt < 9; ++nt) sacc[nt][r] *= inv;
        }
        // ---- P -> private LDS slab (only this wave reads it; no barrier) ----
        u16* pt = &sm[BP_OFF + t * BP_TILE];
#pragma unroll
        for (int r = 0; r < 4; ++r) {
            int row = lq * 4 + r;
#pragma unroll
            for (int nt = 0; nt < 9; ++nt)
                pt[row * BVT_STR + nt * 16 + l15] = f2bf(sacc[nt][r]);
        }
        // ---- PV: K=144 (4 full kt + masked kt4) ----
        f32x4 pv[2] = {fzero, fzero};
#pragma unroll
        for (int kt = 0; kt < 4; ++kt) {
            bf16x8 a = *(const bf16x8*)&pt[l15 * BVT_STR + kt * 32 + lq * 8];
#pragma unroll
            for (int dt = 0; dt < 2; ++dt) {
                bf16x8 bb = *(const bf16x8*)&sm[BVT_OFF + (dt * 16 + l15) * BVT_STR + kt * 32 + lq * 8];
                pv[dt] = __builtin_amdgcn_mfma_f32_16x16x32_bf16(a, bb, pv[dt], 0, 0, 0);
            }
        }
        bf16x8 a4 = zero_frag();
        if (lq < 2) a4 = *(const bf16x8*)&pt[l15 * BVT_STR + 128 + lq * 8];
#pragma unroll
        for (int dt = 0; dt < 2; ++dt) {
            bf16x8 bb = *(const bf16x8*)&sm[BVT_OFF + (dt * 16 + l15) * BVT_STR + 128 + (lq & 1) * 8];
            pv[dt] = __builtin_amdgcn_mfma_f32_16x16x32_bf16(a4, bb, pv[dt], 0, 0, 0);
        }
        // ---- O store, head-major o_ws[h][bw][144][32] ----
        u16* op = o_ws + (((size_t)h * NBLK + bwlin) * NTOK + t * 16 + lq * 4) * HDIM;
#pragma unroll
        for (int dt = 0; dt < 2; ++dt)
#pragma unroll
            for (int r = 0; r < 4; ++r)
                op[r * HDIM + dt * 16 + l15] = f2bf(pv[dt][r]);
    }
}

// =================== kernel C: output projection GEMM (R4, known-good) ===================
#define PW_STR 200
__global__ __launch_bounds__(512, 4)
void proj_gemm(const u16* __restrict__ o_ws, const u16* __restrict__ projw_c,
               const u16* __restrict__ projb_c, void* __restrict__ out,
               const int* __restrict__ mode) {
    __shared__ __align__(16) u16 smW[CDIM * PW_STR];   // 76,800 B
    const int fm   = mode[0];
    const int tid  = threadIdx.x;
    const int wv   = tid >> 6;
    const int lane = tid & 63;
    const int l15  = lane & 15;
    const int lq   = lane >> 4;

    for (int i = tid; i < CDIM * CDIM / 8; i += 512) {   // 4608
        int r = i / 24, c8 = (i % 24) * 8;
        *(uint4*)&smW[r * PW_STR + c8] = *(const uint4*)(projw_c + (size_t)r * CDIM + c8);
    }
    __syncthreads();

    const int tile = blockIdx.x * 8 + wv;             // 0..17279
    const int win  = tile / 9;
    const int trow = (tile % 9) * 16;
    const f32x4 fzero = {0.f, 0.f, 0.f, 0.f};

    bf16x8 a[6];
#pragma unroll
    for (int kt = 0; kt < 6; ++kt)
        a[kt] = *(const bf16x8*)&o_ws[((size_t)kt * NBLK + win) * (NTOK * HDIM)
                                      + (trow + l15) * HDIM + lq * 8];

    f32x4 acc[12];
#pragma unroll
    for (int nt = 0; nt < 12; ++nt) acc[nt] = fzero;
#pragma unroll
    for (int kt = 0; kt < 6; ++kt) {
#pragma unroll
        for (int nt = 0; nt < 12; ++nt) {
            bf16x8 bb = *(const bf16x8*)&smW[(nt * 16 + l15) * PW_STR + kt * 32 + lq * 8];
            acc[nt] = __builtin_amdgcn_mfma_f32_16x16x32_bf16(a[kt], bb, acc[nt], 0, 0, 0);
        }
    }
    const size_t rb = (size_t)win * (NTOK * CDIM) + (size_t)trow * CDIM;
#pragma unroll
    for (int nt = 0; nt < 12; ++nt) {
        int col = nt * 16 + l15;
        float pb = bf2f(projb_c[col]);
#pragma unroll
        for (int r = 0; r < 4; ++r)
            st_s(out, rb + (lq * 4 + r) * CDIM + col, acc[nt][r] + pb, fm);
    }
}

// =================== fallback tier 2: R4 fused attn (needs only o_ws tier) ===================
#define AQ_OFF  0
#define AK_OFF  5760
#define AQK_STR 40
#define APB_OFF 11520
#define AP_STR  152
#define AW_STR  200
#define AVT_OFF 33408
#define AVT_STR 152
#define ASM_TOT 38272

__global__ __launch_bounds__(576, 8)
void attn_qkv(const void* __restrict__ x,
              const u16* __restrict__ qkvw_c, const u16* __restrict__ qkvb_c,
              const u16* __restrict__ bias_f, u16* __restrict__ o_ws,
              const int* __restrict__ mode) {
    __shared__ __align__(16) u16 sm[ASM_TOT];

    const int fm   = mode[0];
    const int tid  = threadIdx.x;
    const int wv   = tid >> 6;
    const int lane = tid & 63;
    const int l15  = lane & 15;
    const int lq   = lane >> 4;

    const int blk   = blockIdx.x;
    const int virt  = (blk & 7) * (NBLK / 8) + (blk >> 3);
    const int w     = virt / NB;
    const int bwlin = (virt % NB) * NWIN + w;

    const size_t xrow = ((size_t)bwlin * NTOK + wv * 16 + l15) * CDIM;
    const f32x4 fzero = {0.f, 0.f, 0.f, 0.f};

    for (int h = 0; h < NHEADS; ++h) {
        const int hoff = h * HDIM;

        for (int i = tid; i < 96 * CDIM / 8; i += 576) {
            int r = i / 24, c8 = (i % 24) * 8;
            int grow = (r >> 5) * CDIM + hoff + (r & 31);
            *(uint4*)&sm[APB_OFF + r * AW_STR + c8] =
                *(const uint4*)(qkvw_c + (size_t)grow * CDIM + c8);
        }
        __syncthreads();

        {
            f32x4 acc[6];
#pragma unroll
            for (int nt = 0; nt < 6; ++nt) acc[nt] = fzero;
#pragma unroll
            for (int kt = 0; kt < 6; ++kt) {
                bf16x8 xf = ld_x_frag(x, xrow, kt * 32 + lq * 8, fm);
#pragma unroll
                for (int nt = 0; nt < 6; ++nt) {
                    bf16x8 bb = *(const bf16x8*)&sm[APB_OFF + (nt * 16 + l15) * AW_STR + kt * 32 + lq * 8];
                    acc[nt] = __builtin_amdgcn_mfma_f32_16x16x32_bf16(xf, bb, acc[nt], 0, 0, 0);
                }
            }
#pragma unroll
            for (int nt = 0; nt < 6; ++nt) {
                int col = nt * 16 + l15;
                int s = col >> 5, d = col & 31;
                float bias = bf2f(qkvb_c[s * CDIM + hoff + d]);
#pragma unroll
                for (int r = 0; r < 4; ++r) {
                    int row = wv * 16 + lq * 4 + r;
                    float v = acc[nt][r] + bias;
                    if (s == 0)      sm[AQ_OFF + row * AQK_STR + d] = f2bf(v * SCALE);
                    else if (s == 1) sm[AK_OFF + row * AQK_STR + d] = f2bf(v);
                    else             sm[AVT_OFF + d * AVT_STR + row] = f2bf(v);
                }
            }
        }
        __syncthreads();

        f32x4 sacc[9];
        {
            bf16x8 a = *(const bf16x8*)&sm[AQ_OFF + (wv * 16 + l15) * AQK_STR + lq * 8];
#pragma unroll
            for (int nt = 0; nt < 9; ++nt) {
                bf16x8 bb = *(const bf16x8*)&sm[AK_OFF + (nt * 16 + l15) * AQK_STR + lq * 8];
                sacc[nt] = __builtin_amdgcn_mfma_f32_16x16x32_bf16(a, bb, fzero, 0, 0, 0);
            }
            const u16* bf = bias_f + ((size_t)(w * NHEADS + h) * 81 + wv * 9) * 256;
#pragma unroll
            for (int nt = 0; nt < 9; ++nt) {
                u16x4 pk = *(const u16x4*)&bf[nt * 256 + (lane << 2)];
#pragma unroll
                for (int r = 0; r < 4; ++r) sacc[nt][r] += bf2f(pk[r]);
            }
#pragma unroll
            for (int r = 0; r < 4; ++r) {
                float m = -1e30f;
                for (int nt = 0; nt < 9; ++nt) m = fmaxf(m, sacc[nt][r]);
                for (int d = 1; d < 16; d <<= 1) m = fmaxf(m, __shfl_xor(m, d, 64));
                float s = 0.f;
                for (int nt = 0; nt < 9; ++nt) {
                    float e = __expf(sacc[nt][r] - m);
                    sacc[nt][r] = e; s += e;
                }
                for (int d = 1; d < 16; d <<= 1) s += __shfl_xor(s, d, 64);
                float inv = 1.0f / s;
                for (int nt = 0; nt < 9; ++nt) sacc[nt][r] *= inv;
            }
        }

#pragma unroll
        for (int r = 0; r < 4; ++r) {
            int row = wv * 16 + lq * 4 + r;
#pragma unroll
            for (int nt = 0; nt < 9; ++nt)
                sm[APB_OFF + row * AP_STR + nt * 16 + l15] = f2bf(sacc[nt][r]);
        }
        __syncthreads();

        {
            f32x4 pv[2] = {fzero, fzero};
#pragma unroll
            for (int kt = 0; kt < 4; ++kt) {
                bf16x8 a = *(const bf16x8*)&sm[APB_OFF + (wv * 16 + l15) * AP_STR + kt * 32 + lq * 8];
#pragma unroll
                for (int dt = 0; dt < 2; ++dt) {
                    bf16x8 bb = *(const bf16x8*)&sm[AVT_OFF + (dt * 16 + l15) * AVT_STR + kt * 32 + lq * 8];
                    pv[dt] = __builtin_amdgcn_mfma_f32_16x16x32_bf16(a, bb, pv[dt], 0, 0, 0);
                }
            }
            bf16x8 a4 = zero_frag();
            if (lq < 2)
                a4 = *(const bf16x8*)&sm[APB_OFF + (wv * 16 + l15) * AP_STR + 128 + lq * 8];
#pragma unroll
            for (int dt = 0; dt < 2; ++dt) {
                bf16x8 bb = *(const bf16x8*)&sm[AVT_OFF + (dt * 16 + l15) * AVT_STR + 128 + (lq & 1) * 8];
                pv[dt] = __builtin_amdgcn_mfma_f32_16x16x32_bf16(a4, bb, pv[dt], 0, 0, 0);
            }
            u16* op = o_ws + (((size_t)h * NBLK + bwlin) * NTOK + wv * 16 + lq * 4) * HDIM;
#pragma unroll
            for (int dt = 0; dt < 2; ++dt)
#pragma unroll
                for (int r = 0; r < 4; ++r)
                    op[r * HDIM + dt * 16 + l15] = f2bf(pv[dt][r]);
        }
        __syncthreads();
    }
}

// =================== fallback tier 3: generic monolithic (tiny ws) ===================
#define Q_OFF  0
#define K_OFF  5760
#define QK_STR 40
#define P_OFF  11520
#define P_STR  168
#define VT_OFF 35712
#define VT_STR 168
#define OA_OFF 41088
#define OA_STR 200
#define SM_TOT 69888

__global__ __launch_bounds__(576, 3)
void earth_attn_fused(const void* __restrict__ x, const void* __restrict__ qkv_w,
                const void* __restrict__ qkv_b, const void* __restrict__ proj_w,
                const void* __restrict__ proj_b, const void* __restrict__ bias_table,
                const int* __restrict__ pos_index,
                void* __restrict__ out, const int* __restrict__ mode) {
    __shared__ __align__(16) u16 sm[SM_TOT];

    const int fm   = mode[0];
    const int tid  = threadIdx.x;
    const int wv   = tid >> 6;
    const int lane = tid & 63;
    const int l15  = lane & 15;
    const int lq   = lane >> 4;

    const int blk   = blockIdx.x;
    const int virt  = (blk & 7) * (NBLK / 8) + (blk >> 3);
    const int w     = virt / NB;
    const int bwlin = (virt % NB) * NWIN + w;

    {
        uint4 z; z.x = z.y = z.z = z.w = 0u;
        for (int i = tid; i < (32 * VT_STR) / 8; i += 576) *(uint4*)&sm[VT_OFF + i * 8] = z;
    }

    bf16x8 xfrag[6];
    {
        const size_t xrow = ((size_t)bwlin * NTOK + wv * 16 + l15) * CDIM;
#pragma unroll
        for (int kt = 0; kt < 6; ++kt) xfrag[kt] = ld_x_frag(x, xrow, kt * 32 + lq * 8, fm);
    }
    __syncthreads();

    const f32x4 fzero = {0.f, 0.f, 0.f, 0.f};

    for (int h = 0; h < NHEADS; ++h) {
        const int hoff = h * HDIM;

        float bsv[9][4];
#pragma unroll
        for (int nt = 0; nt < 9; ++nt) {
            int col = nt * 16 + l15;
#pragma unroll
            for (int r = 0; r < 4; ++r) {
                int idx = pos_index[(wv * 16 + lq * 4 + r) * NTOK + col];
                bsv[nt][r] = ld_s(bias_table, ((size_t)idx * NWIN + w) * NHEADS + h, fm);
            }
        }

        {
            f32x4 acc[6];
            for (int nt = 0; nt < 6; ++nt) acc[nt] = fzero;
            int wrow[6];
#pragma unroll
            for (int nt = 0; nt < 6; ++nt) {
                int c = nt * 16 + l15, s = c >> 5, d = c & 31;
                wrow[nt] = (s * CDIM + hoff + d) * CDIM;
            }
#pragma unroll
            for (int kt = 0; kt < 6; ++kt) {
#pragma unroll
                for (int nt = 0; nt < 6; ++nt) {
                    bf16x8 bb = ld_frag(qkv_w, (size_t)wrow[nt] + kt * 32 + lq * 8, fm);
                    acc[nt] = __builtin_amdgcn_mfma_f32_16x16x32_bf16(xfrag[kt], bb, acc[nt], 0, 0, 0);
                }
            }
#pragma unroll
            for (int nt = 0; nt < 6; ++nt) {
                int col = nt * 16 + l15;
                int s = col >> 5, d = col & 31;
                float bias = ld_s(qkv_b, s * CDIM + hoff + d, fm);
#pragma unroll
                for (int r = 0; r < 4; ++r) {
                    int row = wv * 16 + lq * 4 + r;
                    float v = acc[nt][r] + bias;
                    if (s == 0)      sm[Q_OFF + row * QK_STR + d] = f2bf(v * SCALE);
                    else if (s == 1) sm[K_OFF + row * QK_STR + d] = f2bf(v);
                    else             sm[VT_OFF + d * VT_STR + row] = f2bf(v);
                }
            }
        }
        __syncthreads();

        f32x4 sacc[9];
        {
            bf16x8 a = *(const bf16x8*)&sm[Q_OFF + (wv * 16 + l15) * QK_STR + lq * 8];
#pragma unroll
            for (int nt = 0; nt < 9; ++nt) {
                bf16x8 bb = *(const bf16x8*)&sm[K_OFF + (nt * 16 + l15) * QK_STR + lq * 8];
                sacc[nt] = __builtin_amdgcn_mfma_f32_16x16x32_bf16(a, bb, fzero, 0, 0, 0);
            }
#pragma unroll
            for (int nt = 0; nt < 9; ++nt)
#pragma unroll
                for (int r = 0; r < 4; ++r) sacc[nt][r] += bsv[nt][r];
#pragma unroll
            for (int r = 0; r < 4; ++r) {
                float m = -1e30f;
                for (int nt = 0; nt < 9; ++nt) m = fmaxf(m, sacc[nt][r]);
                for (int d = 1; d < 16; d <<= 1) m = fmaxf(m, __shfl_xor(m, d, 64));
                float s = 0.f;
                for (int nt = 0; nt < 9; ++nt) {
                    float e = __expf(sacc[nt][r] - m);
                    sacc[nt][r] = e; s += e;
                }
                for (int d = 1; d < 16; d <<= 1) s += __shfl_xor(s, d, 64);
                float inv = 1.0f / s;
                for (int nt = 0; nt < 9; ++nt) sacc[nt][r] *= inv;
            }
        }

#pragma unroll
        for (int r = 0; r < 4; ++r) {
            int row = wv * 16 + lq * 4 + r;
#pragma unroll
            for (int nt = 0; nt < 9; ++nt)
                sm[P_OFF + row * P_STR + nt * 16 + l15] = f2bf(sacc[nt][r]);
            sm[P_OFF + row * P_STR + 144 + l15] = 0;
        }
        __syncthreads();

        f32x4 pv[2] = {fzero, fzero};
#pragma unroll
        for (int kt = 0; kt < 5; ++kt) {
            bf16x8 a = *(const bf16x8*)&sm[P_OFF + (wv * 16 + l15) * P_STR + kt * 32 + lq * 8];
#pragma unroll
            for (int dt = 0; dt < 2; ++dt) {
                bf16x8 bb = *(const bf16x8*)&sm[VT_OFF + (dt * 16 + l15) * VT_STR + kt * 32 + lq * 8];
                pv[dt] = __builtin_amdgcn_mfma_f32_16x16x32_bf16(a, bb, pv[dt], 0, 0, 0);
            }
        }

#pragma unroll
        for (int dt = 0; dt < 2; ++dt)
#pragma unroll
            for (int r = 0; r < 4; ++r) {
                int row = wv * 16 + lq * 4 + r;
                sm[OA_OFF + row * OA_STR + hoff + dt * 16 + l15] = f2bf(pv[dt][r]);
            }
        __syncthreads();
    }

    f32x4 oacc[12];
    for (int nt = 0; nt < 12; ++nt) oacc[nt] = fzero;
    {
        bf16x8 a[6];
#pragma unroll
        for (int kt = 0; kt < 6; ++kt)
            a[kt] = *(const bf16x8*)&sm[OA_OFF + (wv * 16 + l15) * OA_STR + kt * 32 + lq * 8];
#pragma unroll
        for (int kt = 0; kt < 6; ++kt) {
#pragma unroll
            for (int nt = 0; nt < 12; ++nt) {
                bf16x8 bb = ld_frag(proj_w, (size_t)(nt * 16 + l15) * CDIM + kt * 32 + lq * 8, fm);
                oacc[nt] = __builtin_amdgcn_mfma_f32_16x16x32_bf16(a[kt], bb, oacc[nt], 0, 0, 0);
            }
        }
    }

    const size_t obase = (size_t)bwlin * (NTOK * CDIM);
#pragma unroll
    for (int nt = 0; nt < 12; ++nt) {
        int col = nt * 16 + l15;
        float pb = ld_s(proj_b, col, fm);
#pragma unroll
        for (int r = 0; r < 4; ++r) {
            int row = wv * 16 + lq * 4 + r;
            st_s(out, obase + row * CDIM + col, oacc[nt][r] + pb, fm);
        }
    }
}

extern "C" void kernel_launch(void* const* d_in, const int* in_sizes, int n_in,
                              void* d_out, int out_size, void* d_ws, size_t ws_size,
                              hipStream_t stream) {
    const void* x          = d_in[0];
    const void* qkv_w      = d_in[1];
    const void* qkv_b      = d_in[2];
    const void* proj_w     = d_in[3];
    const void* proj_b     = d_in[4];
    const void* bias_table = d_in[5];
    const int*  pos_index  = (const int*)d_in[6];

    // ws: [16B flag][bias_f 15.93MB][weights ~289KB][o_ws 106MB][q_ws][k_ws][v_ws]
    int*  mode_flag = (int*)d_ws;
    char* p         = (char*)d_ws + 16;
    const size_t biasf_bytes = (size_t)NWIN * NHEADS * 81 * 256 * sizeof(u16);
    u16* bias_f = (u16*)p;            p += biasf_bytes;
    u16* qkvw_c = (u16*)p;            p += (size_t)3 * CDIM * CDIM * sizeof(u16);
    u16* projw_c = (u16*)p;           p += (size_t)CDIM * CDIM * sizeof(u16);
    u16* qkvb_c = (u16*)p;            p += 3 * CDIM * sizeof(u16);
    u16* projb_c = (u16*)p;           p += CDIM * sizeof(u16);
    const size_t plane = (size_t)NBLK * NHEADS * NTOK * HDIM * sizeof(u16);  // 106 MB
    u16* o_ws = (u16*)p;              p += plane;
    const size_t need_split2 = (size_t)(p - (char*)d_ws);
    u16* q_ws = (u16*)p;              p += plane;
    u16* k_ws = (u16*)p;              p += plane;
    u16* v_ws = (u16*)p;              p += plane;
    const size_t need_split3 = (size_t)(p - (char*)d_ws);

    int use_split2 = (ws_size >= need_split2) ? 1 : 0;
    int use_split3 = (ws_size >= need_split3) ? 1 : 0;

    detect_mode<<<dim3(1), dim3(256), 0, stream>>>((const u16*)qkv_w, mode_flag);

    if (use_split2) {
        bias_gather3<<<dim3(NWIN * NHEADS), dim3(256), 0, stream>>>(
            bias_table, pos_index, bias_f, mode_flag);
        wconv<<<dim3(192), dim3(256), 0, stream>>>(
            qkv_w, qkv_b, proj_w, proj_b, qkvw_c, projw_c, qkvb_c, projb_c, mode_flag);
    }

    if (use_split3) {
        qkv_gemm<<<dim3(NBLK), dim3(512), 0, stream>>>(
            x, qkvw_c, qkvb_c, q_ws, k_ws, v_ws, mode_flag);
        attn_bh<<<dim3(NBLK * NHEADS), dim3(512), 0, stream>>>(
            q_ws, k_ws, v_ws, bias_f, o_ws);
        proj_gemm<<<dim3(NBLK * 9 / 8), dim3(512), 0, stream>>>(
            o_ws, projw_c, projb_c, d_out, mode_flag);
    } else if (use_split2) {
        attn_qkv<<<dim3(NBLK), dim3(576), 0, stream>>>(
            x, qkvw_c, qkvb_c, bias_f, o_ws, mode_flag);
        proj_gemm<<<dim3(NBLK * 9 / 8), dim3(512), 0, stream>>>(
            o_ws, projw_c, projb_c, d_out, mode_flag);
    } else {
        earth_attn_fused<<<dim3(NBLK), dim3(576), 0, stream>>>(
            x, qkv_w, qkv_b, proj_w, proj_b, bias_table, pos_index, d_out, mode_flag);
    }
}

// Round 6
// 801.975 us; speedup vs baseline: 2.9695x; 2.9695x over previous
//
#include <hip/hip_runtime.h>

typedef unsigned short u16;
typedef unsigned int u32;

#define NTOK 144
#define CDIM 192
#define NHEADS 6
#define HDIM 32
#define NWIN 64
#define NB 30
#define NBLK (NB * NWIN)
#define TABLE_N 3312
#define SCALE 0.17677669529663687f

typedef __bf16 bf16x8 __attribute__((ext_vector_type(8)));
typedef u16 u16x8 __attribute__((ext_vector_type(8)));
typedef u16 u16x4 __attribute__((ext_vector_type(4)));
typedef float f32x4 __attribute__((ext_vector_type(4)));

__device__ __forceinline__ float bf2f(u16 u) {
    union { u32 i; float f; } v; v.i = ((u32)u) << 16; return v.f;
}
__device__ __forceinline__ u16 f2bf(float f) {
    union { float f; u32 i; } v; v.f = f;
    u32 r = v.i + 0x7FFFu + ((v.i >> 16) & 1u);   // RNE
    return (u16)(r >> 16);
}

// -------- dtype-robust accessors (fm==1: raw buffers are fp32) --------
__device__ __forceinline__ bf16x8 ld_frag(const void* base, size_t idx, int fm) {
    if (!fm) return *(const bf16x8*)((const u16*)base + idx);
    const float* pf = (const float*)base;
    u16x8 t;
#pragma unroll
    for (int j = 0; j < 8; ++j) t[j] = f2bf(pf[idx + j]);
    union { u16x8 u; bf16x8 b; } cv; cv.u = t; return cv.b;
}
__device__ __forceinline__ float ld_s(const void* base, size_t idx, int fm) {
    return fm ? ((const float*)base)[idx] : bf2f(((const u16*)base)[idx]);
}
__device__ __forceinline__ void st_s(void* base, size_t idx, float v, int fm) {
    if (fm) ((float*)base)[idx] = v; else ((u16*)base)[idx] = f2bf(v);
}
__device__ __forceinline__ bf16x8 zero_frag() {
    union { u16x8 u; bf16x8 b; } cv;
#pragma unroll
    for (int j = 0; j < 8; ++j) cv.u[j] = 0;
    return cv.b;
}
// x A-fragment loader (16B worth of bf16; converts when fm)
__device__ __forceinline__ bf16x8 ld_x_frag(const void* x, size_t rowbase, int off, int fm) {
    if (!fm) return *(const bf16x8*)((const u16*)x + rowbase + off);
    const float* xs = (const float*)x + rowbase + off;
    const float4 a0 = *(const float4*)xs;
    const float4 a1 = *(const float4*)(xs + 4);
    union { u16x8 u; bf16x8 b; } cv;
    cv.u[0] = f2bf(a0.x); cv.u[1] = f2bf(a0.y); cv.u[2] = f2bf(a0.z); cv.u[3] = f2bf(a0.w);
    cv.u[4] = f2bf(a1.x); cv.u[5] = f2bf(a1.y); cv.u[6] = f2bf(a1.z); cv.u[7] = f2bf(a1.w);
    return cv.b;
}

// -------- detector: bf16 vs fp32 input encoding --------
__global__ void detect_mode(const u16* __restrict__ w, int* __restrict__ flag) {
    __shared__ int cnt;
    if (threadIdx.x == 0) cnt = 0;
    __syncthreads();
    int h = 0;
    for (int i = threadIdx.x; i < 4096; i += 256) {
        int e = (w[i] >> 7) & 0xFF;
        if (e >= 0x8E) h++;
    }
    atomicAdd(&cnt, h);
    __syncthreads();
    if (threadIdx.x == 0) flag[0] = (cnt > 64) ? 1 : 0;
}

// -------- prologue: bias in MFMA FRAGMENT layout --------
// bias_f[w][h][T(9)][nt(9)][lane(64)][r(4)] bf16: per (T,nt) a lane reads its 4
// C-frag bias values as one contiguous 8B load.
__global__ void bias_gather3(const void* __restrict__ table, const int* __restrict__ pos,
                             u16* __restrict__ bias_f, const int* __restrict__ mode) {
    __shared__ u16 smT[TABLE_N];
    const int fm = mode[0];
    const int w = blockIdx.x / NHEADS, h = blockIdx.x % NHEADS;
    for (int t = threadIdx.x; t < TABLE_N; t += 256) {
        size_t j = (size_t)t * (NWIN * NHEADS) + w * NHEADS + h;
        smT[t] = fm ? f2bf(((const float*)table)[j]) : ((const u16*)table)[j];
    }
    __syncthreads();
    u16* o = bias_f + (size_t)(w * NHEADS + h) * (81 * 256);
    for (int i = threadIdx.x; i < 81 * 256; i += 256) {
        int T = i / 2304, rem2 = i % 2304;
        int nt = rem2 >> 8, lane = (rem2 >> 2) & 63, r = rem2 & 3;
        int row = T * 16 + (lane >> 4) * 4 + r;
        int col = nt * 16 + (lane & 15);
        o[i] = smT[pos[row * NTOK + col]];
    }
}

// -------- prologue: canonical bf16 weights in workspace (one-time) --------
__global__ void wconv(const void* __restrict__ qkv_w, const void* __restrict__ qkv_b,
                      const void* __restrict__ proj_w, const void* __restrict__ proj_b,
                      u16* __restrict__ qkvw_c, u16* __restrict__ projw_c,
                      u16* __restrict__ qkvb_c, u16* __restrict__ projb_c,
                      const int* __restrict__ mode) {
    const int fm = mode[0];
    const int gid = blockIdx.x * blockDim.x + threadIdx.x;
    const int np  = gridDim.x * blockDim.x;
    const int NQW = 3 * CDIM * CDIM, NPW = CDIM * CDIM;
    if (fm) {
        const float* a = (const float*)qkv_w;
        const float* b = (const float*)proj_w;
        const float* c = (const float*)qkv_b;
        const float* d = (const float*)proj_b;
        for (int i = gid; i < NQW; i += np) qkvw_c[i] = f2bf(a[i]);
        for (int i = gid; i < NPW; i += np) projw_c[i] = f2bf(b[i]);
        for (int i = gid; i < 3 * CDIM; i += np) qkvb_c[i] = f2bf(c[i]);
        for (int i = gid; i < CDIM; i += np) projb_c[i] = f2bf(d[i]);
    } else {
        const u16* a = (const u16*)qkv_w;
        const u16* b = (const u16*)proj_w;
        const u16* c = (const u16*)qkv_b;
        const u16* d = (const u16*)proj_b;
        for (int i = gid; i < NQW; i += np) qkvw_c[i] = a[i];
        for (int i = gid; i < NPW; i += np) projw_c[i] = b[i];
        for (int i = gid; i < 3 * CDIM; i += np) qkvb_c[i] = c[i];
        for (int i = gid; i < CDIM; i += np) projb_c[i] = d[i];
    }
}

// =================== 3-split kernel A: QKV projection GEMM (v2, no-spill) ===================
// 576 thr (9 waves, 1 M-tile per wave) — exact geometry of R4's proven attn_qkv
// (VGPR 60, no spill). x A-fragments loaded ONCE per block and held in registers
// across all 6 heads (x HBM traffic 6x -> 1x). W head-slice staged in LDS.
// Writes q (pre-scaled) / k / v as bf16 [bw][h][144][32].
#define GW_STR 200
__global__ __launch_bounds__(576, 8)
void qkv_gemm(const void* __restrict__ x,
              const u16* __restrict__ qkvw_c, const u16* __restrict__ qkvb_c,
              u16* __restrict__ q_ws, u16* __restrict__ k_ws, u16* __restrict__ v_ws,
              const int* __restrict__ mode) {
    __shared__ __align__(16) u16 smW[96 * GW_STR];   // 38,400 B

    const int fm   = mode[0];
    const int tid  = threadIdx.x;
    const int wv   = tid >> 6;       // 0..8 (M-tile owner)
    const int lane = tid & 63;
    const int l15  = lane & 15;
    const int lq   = lane >> 4;

    const int blk   = blockIdx.x;                       // 0..1919
    const int virt  = (blk & 7) * (NBLK / 8) + (blk >> 3);
    const int w     = virt / NB;
    const int bwlin = (virt % NB) * NWIN + w;

    // x tile -> registers ONCE (persistent across heads)
    bf16x8 xfrag[6];
    {
        const size_t xrow = ((size_t)bwlin * NTOK + wv * 16 + l15) * CDIM;
#pragma unroll
        for (int kt = 0; kt < 6; ++kt) xfrag[kt] = ld_x_frag(x, xrow, kt * 32 + lq * 8, fm);
    }

    const f32x4 fzero = {0.f, 0.f, 0.f, 0.f};

    for (int h = 0; h < NHEADS; ++h) {
        const int hoff = h * HDIM;

        // stage W head-slice (96x192) -> LDS [96][200]
        for (int i = tid; i < 96 * CDIM / 8; i += 576) {      // 2304 = 4*576
            int r = i / 24, c8 = (i % 24) * 8;
            int grow = (r >> 5) * CDIM + hoff + (r & 31);
            *(uint4*)&smW[r * GW_STR + c8] = *(const uint4*)(qkvw_c + (size_t)grow * CDIM + c8);
        }
        __syncthreads();                                     // W staged

        f32x4 acc[6];
#pragma unroll
        for (int nt = 0; nt < 6; ++nt) acc[nt] = fzero;
#pragma unroll
        for (int kt = 0; kt < 6; ++kt) {
#pragma unroll
            for (int nt = 0; nt < 6; ++nt) {
                bf16x8 bb = *(const bf16x8*)&smW[(nt * 16 + l15) * GW_STR + kt * 32 + lq * 8];
                acc[nt] = __builtin_amdgcn_mfma_f32_16x16x32_bf16(xfrag[kt], bb, acc[nt], 0, 0, 0);
            }
        }
        const size_t obase = ((size_t)bwlin * NHEADS + h) * (NTOK * HDIM);
#pragma unroll
        for (int nt = 0; nt < 6; ++nt) {
            int col = nt * 16 + l15;         // 0..95
            int s = col >> 5, d = col & 31;
            float bias = bf2f(qkvb_c[s * CDIM + hoff + d]);
#pragma unroll
            for (int r = 0; r < 4; ++r) {
                int row = wv * 16 + lq * 4 + r;
                float v = acc[nt][r] + bias;
                size_t idx = obase + (size_t)row * HDIM + d;
                if (s == 0)      q_ws[idx] = f2bf(v * SCALE);
                else if (s == 1) k_ws[idx] = f2bf(v);
                else             v_ws[idx] = f2bf(v);
            }
        }
        __syncthreads();   // all reads of W done before restage
    }
}

// =================== 3-split kernel B: per-(window,head) attention ===================
// 11520 blocks, 512 thr (8 waves). ONE barrier per block (after K/vT staging).
// Each wave: QK^T -> +bias -> softmax (regs) -> P (private LDS slab, no barrier)
// -> PV -> O store. LDS: K[144][40]@0, vT[32][152]@5760, P[9][16][152]@10624.
#define BK_OFF  0
#define BK_STR  40
#define BVT_OFF 5760
#define BVT_STR 152
#define BP_OFF  10624
#define BP_TILE 2432     // 16*152
#define BSM_TOT 32512    // u16 = 65,024 B -> 2 blocks/CU

__global__ __launch_bounds__(512, 4)
void attn_bh(const u16* __restrict__ q_ws, const u16* __restrict__ k_ws,
             const u16* __restrict__ v_ws, const u16* __restrict__ bias_f,
             u16* __restrict__ o_ws) {
    __shared__ __align__(16) u16 sm[BSM_TOT];

    const int tid  = threadIdx.x;
    const int wv   = tid >> 6;       // 0..7
    const int lane = tid & 63;
    const int l15  = lane & 15;
    const int lq   = lane >> 4;

    // XCD-chunked; within chunk order (w, h, b) so bias_f slice is L2-hot
    const int blk  = blockIdx.x;                         // 0..11519
    const int virt = (blk & 7) * (NBLK * NHEADS / 8) + (blk >> 3);
    const int w    = virt / (NB * NHEADS);
    const int rem  = virt % (NB * NHEADS);
    const int h    = rem / NB;
    const int b    = rem % NB;
    const int bwlin = b * NWIN + w;

    const size_t kvbase = ((size_t)bwlin * NHEADS + h) * (NTOK * HDIM);

    // stage K [144][32] -> LDS [144][40]
    for (int i = tid; i < 576; i += 512) {
        int r = i >> 2, c8 = (i & 3) * 8;
        *(uint4*)&sm[BK_OFF + r * BK_STR + c8] = *(const uint4*)(k_ws + kvbase + (size_t)r * HDIM + c8);
    }
    // stage v [144][32] -> vT LDS [32][152] (transpose via scalar writes)
    for (int i = tid; i < 576; i += 512) {
        int m = i >> 2, c8 = (i & 3) * 8;
        u16x8 vv = *(const u16x8*)(v_ws + kvbase + (size_t)m * HDIM + c8);
#pragma unroll
        for (int j = 0; j < 8; ++j)
            sm[BVT_OFF + (c8 + j) * BVT_STR + m] = vv[j];
    }
    __syncthreads();                                     // the only barrier

    const f32x4 fzero = {0.f, 0.f, 0.f, 0.f};

    for (int t = wv; t < 9; t += 8) {                    // wave0 also does tile 8
        // ---- QK^T: a from global q (1 b128), b from K LDS ----
        f32x4 sacc[9];
        {
            bf16x8 a = *(const bf16x8*)(q_ws + kvbase + (size_t)(t * 16 + l15) * HDIM + lq * 8);
#pragma unroll
            for (int nt = 0; nt < 9; ++nt) {
                bf16x8 bb = *(const bf16x8*)&sm[BK_OFF + (nt * 16 + l15) * BK_STR + lq * 8];
                sacc[nt] = __builtin_amdgcn_mfma_f32_16x16x32_bf16(a, bb, fzero, 0, 0, 0);
            }
        }
        // ---- + bias (fragment-layout coalesced) ----
        {
            const u16* bf = bias_f + ((size_t)(w * NHEADS + h) * 81 + t * 9) * 256;
#pragma unroll
            for (int nt = 0; nt < 9; ++nt) {
                u16x4 pk = *(const u16x4*)&bf[nt * 256 + (lane << 2)];
#pragma unroll
                for (int r = 0; r < 4; ++r) sacc[nt][r] += bf2f(pk[r]);
            }
        }
        // ---- softmax (registers, 16-lane row groups) ----
#pragma unroll
        for (int r = 0; r < 4; ++r) {
            float m = -1e30f;
            for (int nt = 0; nt < 9; ++nt) m = fmaxf(m, sacc[nt][r]);
            for (int d = 1; d < 16; d <<= 1) m = fmaxf(m, __shfl_xor(m, d, 64));
            float s = 0.f;
            for (int nt = 0; nt < 9; ++nt) {
                float e = __expf(sacc[nt][r] - m);
                sacc[nt][r] = e; s += e;
            }
            for (int d = 1; d < 16; d <<= 1) s += __shfl_xor(s, d, 64);
            float inv = 1.0f / s;
            for (int nt = 0; nt < 9; ++nt) sacc[nt][r] *= inv;
        }
        // ---- P -> private LDS slab (only this wave reads it; no barrier) ----
        u16* pt = &sm[BP_OFF + t * BP_TILE];
#pragma unroll
        for (int r = 0; r < 4; ++r) {
            int row = lq * 4 + r;
#pragma unroll
            for (int nt = 0; nt < 9; ++nt)
                pt[row * BVT_STR + nt * 16 + l15] = f2bf(sacc[nt][r]);
        }
        // ---- PV: K=144 (4 full kt + masked kt4) ----
        f32x4 pv[2] = {fzero, fzero};
#pragma unroll
        for (int kt = 0; kt < 4; ++kt) {
            bf16x8 a = *(const bf16x8*)&pt[l15 * BVT_STR + kt * 32 + lq * 8];
#pragma unroll
            for (int dt = 0; dt < 2; ++dt) {
                bf16x8 bb = *(const bf16x8*)&sm[BVT_OFF + (dt * 16 + l15) * BVT_STR + kt * 32 + lq * 8];
                pv[dt] = __builtin_amdgcn_mfma_f32_16x16x32_bf16(a, bb, pv[dt], 0, 0, 0);
            }
        }
        bf16x8 a4 = zero_frag();
        if (lq < 2) a4 = *(const bf16x8*)&pt[l15 * BVT_STR + 128 + lq * 8];
#pragma unroll
        for (int dt = 0; dt < 2; ++dt) {
            bf16x8 bb = *(const bf16x8*)&sm[BVT_OFF + (dt * 16 + l15) * BVT_STR + 128 + (lq & 1) * 8];
            pv[dt] = __builtin_amdgcn_mfma_f32_16x16x32_bf16(a4, bb, pv[dt], 0, 0, 0);
        }
        // ---- O store, head-major o_ws[h][bw][144][32] ----
        u16* op = o_ws + (((size_t)h * NBLK + bwlin) * NTOK + t * 16 + lq * 4) * HDIM;
#pragma unroll
        for (int dt = 0; dt < 2; ++dt)
#pragma unroll
            for (int r = 0; r < 4; ++r)
                op[r * HDIM + dt * 16 + l15] = f2bf(pv[dt][r]);
    }
}

// =================== kernel C: output projection GEMM (known-good) ===================
#define PW_STR 200
__global__ __launch_bounds__(512, 4)
void proj_gemm(const u16* __restrict__ o_ws, const u16* __restrict__ projw_c,
               const u16* __restrict__ projb_c, void* __restrict__ out,
               const int* __restrict__ mode) {
    __shared__ __align__(16) u16 smW[CDIM * PW_STR];   // 76,800 B
    const int fm   = mode[0];
    const int tid  = threadIdx.x;
    const int wv   = tid >> 6;
    const int lane = tid & 63;
    const int l15  = lane & 15;
    const int lq   = lane >> 4;

    for (int i = tid; i < CDIM * CDIM / 8; i += 512) {   // 4608
        int r = i / 24, c8 = (i % 24) * 8;
        *(uint4*)&smW[r * PW_STR + c8] = *(const uint4*)(projw_c + (size_t)r * CDIM + c8);
    }
    __syncthreads();

    const int tile = blockIdx.x * 8 + wv;             // 0..17279
    const int win  = tile / 9;
    const int trow = (tile % 9) * 16;
    const f32x4 fzero = {0.f, 0.f, 0.f, 0.f};

    bf16x8 a[6];
#pragma unroll
    for (int kt = 0; kt < 6; ++kt)
        a[kt] = *(const bf16x8*)&o_ws[((size_t)kt * NBLK + win) * (NTOK * HDIM)
                                      + (trow + l15) * HDIM + lq * 8];

    f32x4 acc[12];
#pragma unroll
    for (int nt = 0; nt < 12; ++nt) acc[nt] = fzero;
#pragma unroll
    for (int kt = 0; kt < 6; ++kt) {
#pragma unroll
        for (int nt = 0; nt < 12; ++nt) {
            bf16x8 bb = *(const bf16x8*)&smW[(nt * 16 + l15) * PW_STR + kt * 32 + lq * 8];
            acc[nt] = __builtin_amdgcn_mfma_f32_16x16x32_bf16(a[kt], bb, acc[nt], 0, 0, 0);
        }
    }
    const size_t rb = (size_t)win * (NTOK * CDIM) + (size_t)trow * CDIM;
#pragma unroll
    for (int nt = 0; nt < 12; ++nt) {
        int col = nt * 16 + l15;
        float pb = bf2f(projb_c[col]);
#pragma unroll
        for (int r = 0; r < 4; ++r)
            st_s(out, rb + (lq * 4 + r) * CDIM + col, acc[nt][r] + pb, fm);
    }
}

// =================== fallback tier 2: R4 fused attn (needs only o_ws tier) ===================
#define AQ_OFF  0
#define AK_OFF  5760
#define AQK_STR 40
#define APB_OFF 11520
#define AP_STR  152
#define AW_STR  200
#define AVT_OFF 33408
#define AVT_STR 152
#define ASM_TOT 38272

__global__ __launch_bounds__(576, 8)
void attn_qkv(const void* __restrict__ x,
              const u16* __restrict__ qkvw_c, const u16* __restrict__ qkvb_c,
              const u16* __restrict__ bias_f, u16* __restrict__ o_ws,
              const int* __restrict__ mode) {
    __shared__ __align__(16) u16 sm[ASM_TOT];

    const int fm   = mode[0];
    const int tid  = threadIdx.x;
    const int wv   = tid >> 6;
    const int lane = tid & 63;
    const int l15  = lane & 15;
    const int lq   = lane >> 4;

    const int blk   = blockIdx.x;
    const int virt  = (blk & 7) * (NBLK / 8) + (blk >> 3);
    const int w     = virt / NB;
    const int bwlin = (virt % NB) * NWIN + w;

    const size_t xrow = ((size_t)bwlin * NTOK + wv * 16 + l15) * CDIM;
    const f32x4 fzero = {0.f, 0.f, 0.f, 0.f};

    for (int h = 0; h < NHEADS; ++h) {
        const int hoff = h * HDIM;

        for (int i = tid; i < 96 * CDIM / 8; i += 576) {
            int r = i / 24, c8 = (i % 24) * 8;
            int grow = (r >> 5) * CDIM + hoff + (r & 31);
            *(uint4*)&sm[APB_OFF + r * AW_STR + c8] =
                *(const uint4*)(qkvw_c + (size_t)grow * CDIM + c8);
        }
        __syncthreads();

        {
            f32x4 acc[6];
#pragma unroll
            for (int nt = 0; nt < 6; ++nt) acc[nt] = fzero;
#pragma unroll
            for (int kt = 0; kt < 6; ++kt) {
                bf16x8 xf = ld_x_frag(x, xrow, kt * 32 + lq * 8, fm);
#pragma unroll
                for (int nt = 0; nt < 6; ++nt) {
                    bf16x8 bb = *(const bf16x8*)&sm[APB_OFF + (nt * 16 + l15) * AW_STR + kt * 32 + lq * 8];
                    acc[nt] = __builtin_amdgcn_mfma_f32_16x16x32_bf16(xf, bb, acc[nt], 0, 0, 0);
                }
            }
#pragma unroll
            for (int nt = 0; nt < 6; ++nt) {
                int col = nt * 16 + l15;
                int s = col >> 5, d = col & 31;
                float bias = bf2f(qkvb_c[s * CDIM + hoff + d]);
#pragma unroll
                for (int r = 0; r < 4; ++r) {
                    int row = wv * 16 + lq * 4 + r;
                    float v = acc[nt][r] + bias;
                    if (s == 0)      sm[AQ_OFF + row * AQK_STR + d] = f2bf(v * SCALE);
                    else if (s == 1) sm[AK_OFF + row * AQK_STR + d] = f2bf(v);
                    else             sm[AVT_OFF + d * AVT_STR + row] = f2bf(v);
                }
            }
        }
        __syncthreads();

        f32x4 sacc[9];
        {
            bf16x8 a = *(const bf16x8*)&sm[AQ_OFF + (wv * 16 + l15) * AQK_STR + lq * 8];
#pragma unroll
            for (int nt = 0; nt < 9; ++nt) {
                bf16x8 bb = *(const bf16x8*)&sm[AK_OFF + (nt * 16 + l15) * AQK_STR + lq * 8];
                sacc[nt] = __builtin_amdgcn_mfma_f32_16x16x32_bf16(a, bb, fzero, 0, 0, 0);
            }
            const u16* bf = bias_f + ((size_t)(w * NHEADS + h) * 81 + wv * 9) * 256;
#pragma unroll
            for (int nt = 0; nt < 9; ++nt) {
                u16x4 pk = *(const u16x4*)&bf[nt * 256 + (lane << 2)];
#pragma unroll
                for (int r = 0; r < 4; ++r) sacc[nt][r] += bf2f(pk[r]);
            }
#pragma unroll
            for (int r = 0; r < 4; ++r) {
                float m = -1e30f;
                for (int nt = 0; nt < 9; ++nt) m = fmaxf(m, sacc[nt][r]);
                for (int d = 1; d < 16; d <<= 1) m = fmaxf(m, __shfl_xor(m, d, 64));
                float s = 0.f;
                for (int nt = 0; nt < 9; ++nt) {
                    float e = __expf(sacc[nt][r] - m);
                    sacc[nt][r] = e; s += e;
                }
                for (int d = 1; d < 16; d <<= 1) s += __shfl_xor(s, d, 64);
                float inv = 1.0f / s;
                for (int nt = 0; nt < 9; ++nt) sacc[nt][r] *= inv;
            }
        }

#pragma unroll
        for (int r = 0; r < 4; ++r) {
            int row = wv * 16 + lq * 4 + r;
#pragma unroll
            for (int nt = 0; nt < 9; ++nt)
                sm[APB_OFF + row * AP_STR + nt * 16 + l15] = f2bf(sacc[nt][r]);
        }
        __syncthreads();

        {
            f32x4 pv[2] = {fzero, fzero};
#pragma unroll
            for (int kt = 0; kt < 4; ++kt) {
                bf16x8 a = *(const bf16x8*)&sm[APB_OFF + (wv * 16 + l15) * AP_STR + kt * 32 + lq * 8];
#pragma unroll
                for (int dt = 0; dt < 2; ++dt) {
                    bf16x8 bb = *(const bf16x8*)&sm[AVT_OFF + (dt * 16 + l15) * AVT_STR + kt * 32 + lq * 8];
                    pv[dt] = __builtin_amdgcn_mfma_f32_16x16x32_bf16(a, bb, pv[dt], 0, 0, 0);
                }
            }
            bf16x8 a4 = zero_frag();
            if (lq < 2)
                a4 = *(const bf16x8*)&sm[APB_OFF + (wv * 16 + l15) * AP_STR + 128 + lq * 8];
#pragma unroll
            for (int dt = 0; dt < 2; ++dt) {
                bf16x8 bb = *(const bf16x8*)&sm[AVT_OFF + (dt * 16 + l15) * AVT_STR + 128 + (lq & 1) * 8];
                pv[dt] = __builtin_amdgcn_mfma_f32_16x16x32_bf16(a4, bb, pv[dt], 0, 0, 0);
            }
            u16* op = o_ws + (((size_t)h * NBLK + bwlin) * NTOK + wv * 16 + lq * 4) * HDIM;
#pragma unroll
            for (int dt = 0; dt < 2; ++dt)
#pragma unroll
                for (int r = 0; r < 4; ++r)
                    op[r * HDIM + dt * 16 + l15] = f2bf(pv[dt][r]);
        }
        __syncthreads();
    }
}

// =================== fallback tier 3: generic monolithic (tiny ws) ===================
#define Q_OFF  0
#define K_OFF  5760
#define QK_STR 40
#define P_OFF  11520
#define P_STR  168
#define VT_OFF 35712
#define VT_STR 168
#define OA_OFF 41088
#define OA_STR 200
#define SM_TOT 69888

__global__ __launch_bounds__(576, 3)
void earth_attn_fused(const void* __restrict__ x, const void* __restrict__ qkv_w,
                const void* __restrict__ qkv_b, const void* __restrict__ proj_w,
                const void* __restrict__ proj_b, const void* __restrict__ bias_table,
                const int* __restrict__ pos_index,
                void* __restrict__ out, const int* __restrict__ mode) {
    __shared__ __align__(16) u16 sm[SM_TOT];

    const int fm   = mode[0];
    const int tid  = threadIdx.x;
    const int wv   = tid >> 6;
    const int lane = tid & 63;
    const int l15  = lane & 15;
    const int lq   = lane >> 4;

    const int blk   = blockIdx.x;
    const int virt  = (blk & 7) * (NBLK / 8) + (blk >> 3);
    const int w     = virt / NB;
    const int bwlin = (virt % NB) * NWIN + w;

    {
        uint4 z; z.x = z.y = z.z = z.w = 0u;
        for (int i = tid; i < (32 * VT_STR) / 8; i += 576) *(uint4*)&sm[VT_OFF + i * 8] = z;
    }

    bf16x8 xfrag[6];
    {
        const size_t xrow = ((size_t)bwlin * NTOK + wv * 16 + l15) * CDIM;
#pragma unroll
        for (int kt = 0; kt < 6; ++kt) xfrag[kt] = ld_x_frag(x, xrow, kt * 32 + lq * 8, fm);
    }
    __syncthreads();

    const f32x4 fzero = {0.f, 0.f, 0.f, 0.f};

    for (int h = 0; h < NHEADS; ++h) {
        const int hoff = h * HDIM;

        float bsv[9][4];
#pragma unroll
        for (int nt = 0; nt < 9; ++nt) {
            int col = nt * 16 + l15;
#pragma unroll
            for (int r = 0; r < 4; ++r) {
                int idx = pos_index[(wv * 16 + lq * 4 + r) * NTOK + col];
                bsv[nt][r] = ld_s(bias_table, ((size_t)idx * NWIN + w) * NHEADS + h, fm);
            }
        }

        {
            f32x4 acc[6];
            for (int nt = 0; nt < 6; ++nt) acc[nt] = fzero;
            int wrow[6];
#pragma unroll
            for (int nt = 0; nt < 6; ++nt) {
                int c = nt * 16 + l15, s = c >> 5, d = c & 31;
                wrow[nt] = (s * CDIM + hoff + d) * CDIM;
            }
#pragma unroll
            for (int kt = 0; kt < 6; ++kt) {
#pragma unroll
                for (int nt = 0; nt < 6; ++nt) {
                    bf16x8 bb = ld_frag(qkv_w, (size_t)wrow[nt] + kt * 32 + lq * 8, fm);
                    acc[nt] = __builtin_amdgcn_mfma_f32_16x16x32_bf16(xfrag[kt], bb, acc[nt], 0, 0, 0);
                }
            }
#pragma unroll
            for (int nt = 0; nt < 6; ++nt) {
                int col = nt * 16 + l15;
                int s = col >> 5, d = col & 31;
                float bias = ld_s(qkv_b, s * CDIM + hoff + d, fm);
#pragma unroll
                for (int r = 0; r < 4; ++r) {
                    int row = wv * 16 + lq * 4 + r;
                    float v = acc[nt][r] + bias;
                    if (s == 0)      sm[Q_OFF + row * QK_STR + d] = f2bf(v * SCALE);
                    else if (s == 1) sm[K_OFF + row * QK_STR + d] = f2bf(v);
                    else             sm[VT_OFF + d * VT_STR + row] = f2bf(v);
                }
            }
        }
        __syncthreads();

        f32x4 sacc[9];
        {
            bf16x8 a = *(const bf16x8*)&sm[Q_OFF + (wv * 16 + l15) * QK_STR + lq * 8];
#pragma unroll
            for (int nt = 0; nt < 9; ++nt) {
                bf16x8 bb = *(const bf16x8*)&sm[K_OFF + (nt * 16 + l15) * QK_STR + lq * 8];
                sacc[nt] = __builtin_amdgcn_mfma_f32_16x16x32_bf16(a, bb, fzero, 0, 0, 0);
            }
#pragma unroll
            for (int nt = 0; nt < 9; ++nt)
#pragma unroll
                for (int r = 0; r < 4; ++r) sacc[nt][r] += bsv[nt][r];
#pragma unroll
            for (int r = 0; r < 4; ++r) {
                float m = -1e30f;
                for (int nt = 0; nt < 9; ++nt) m = fmaxf(m, sacc[nt][r]);
                for (int d = 1; d < 16; d <<= 1) m = fmaxf(m, __shfl_xor(m, d, 64));
                float s = 0.f;
                for (int nt = 0; nt < 9; ++nt) {
                    float e = __expf(sacc[nt][r] - m);
                    sacc[nt][r] = e; s += e;
                }
                for (int d = 1; d < 16; d <<= 1) s += __shfl_xor(s, d, 64);
                float inv = 1.0f / s;
                for (int nt = 0; nt < 9; ++nt) sacc[nt][r] *= inv;
            }
        }

#pragma unroll
        for (int r = 0; r < 4; ++r) {
            int row = wv * 16 + lq * 4 + r;
#pragma unroll
            for (int nt = 0; nt < 9; ++nt)
                sm[P_OFF + row * P_STR + nt * 16 + l15] = f2bf(sacc[nt][r]);
            sm[P_OFF + row * P_STR + 144 + l15] = 0;
        }
        __syncthreads();

        f32x4 pv[2] = {fzero, fzero};
#pragma unroll
        for (int kt = 0; kt < 5; ++kt) {
            bf16x8 a = *(const bf16x8*)&sm[P_OFF + (wv * 16 + l15) * P_STR + kt * 32 + lq * 8];
#pragma unroll
            for (int dt = 0; dt < 2; ++dt) {
                bf16x8 bb = *(const bf16x8*)&sm[VT_OFF + (dt * 16 + l15) * VT_STR + kt * 32 + lq * 8];
                pv[dt] = __builtin_amdgcn_mfma_f32_16x16x32_bf16(a, bb, pv[dt], 0, 0, 0);
            }
        }

#pragma unroll
        for (int dt = 0; dt < 2; ++dt)
#pragma unroll
            for (int r = 0; r < 4; ++r) {
                int row = wv * 16 + lq * 4 + r;
                sm[OA_OFF + row * OA_STR + hoff + dt * 16 + l15] = f2bf(pv[dt][r]);
            }
        __syncthreads();
    }

    f32x4 oacc[12];
    for (int nt = 0; nt < 12; ++nt) oacc[nt] = fzero;
    {
        bf16x8 a[6];
#pragma unroll
        for (int kt = 0; kt < 6; ++kt)
            a[kt] = *(const bf16x8*)&sm[OA_OFF + (wv * 16 + l15) * OA_STR + kt * 32 + lq * 8];
#pragma unroll
        for (int kt = 0; kt < 6; ++kt) {
#pragma unroll
            for (int nt = 0; nt < 12; ++nt) {
                bf16x8 bb = ld_frag(proj_w, (size_t)(nt * 16 + l15) * CDIM + kt * 32 + lq * 8, fm);
                oacc[nt] = __builtin_amdgcn_mfma_f32_16x16x32_bf16(a[kt], bb, oacc[nt], 0, 0, 0);
            }
        }
    }

    const size_t obase = (size_t)bwlin * (NTOK * CDIM);
#pragma unroll
    for (int nt = 0; nt < 12; ++nt) {
        int col = nt * 16 + l15;
        float pb = ld_s(proj_b, col, fm);
#pragma unroll
        for (int r = 0; r < 4; ++r) {
            int row = wv * 16 + lq * 4 + r;
            st_s(out, obase + row * CDIM + col, oacc[nt][r] + pb, fm);
        }
    }
}

extern "C" void kernel_launch(void* const* d_in, const int* in_sizes, int n_in,
                              void* d_out, int out_size, void* d_ws, size_t ws_size,
                              hipStream_t stream) {
    const void* x          = d_in[0];
    const void* qkv_w      = d_in[1];
    const void* qkv_b      = d_in[2];
    const void* proj_w     = d_in[3];
    const void* proj_b     = d_in[4];
    const void* bias_table = d_in[5];
    const int*  pos_index  = (const int*)d_in[6];

    // ws: [16B flag][bias_f 15.93MB][weights ~289KB][o_ws 106MB][q_ws][k_ws][v_ws]
    int*  mode_flag = (int*)d_ws;
    char* p         = (char*)d_ws + 16;
    const size_t biasf_bytes = (size_t)NWIN * NHEADS * 81 * 256 * sizeof(u16);
    u16* bias_f = (u16*)p;            p += biasf_bytes;
    u16* qkvw_c = (u16*)p;            p += (size_t)3 * CDIM * CDIM * sizeof(u16);
    u16* projw_c = (u16*)p;           p += (size_t)CDIM * CDIM * sizeof(u16);
    u16* qkvb_c = (u16*)p;            p += 3 * CDIM * sizeof(u16);
    u16* projb_c = (u16*)p;           p += CDIM * sizeof(u16);
    const size_t plane = (size_t)NBLK * NHEADS * NTOK * HDIM * sizeof(u16);  // 106 MB
    u16* o_ws = (u16*)p;              p += plane;
    const size_t need_split2 = (size_t)(p - (char*)d_ws);
    u16* q_ws = (u16*)p;              p += plane;
    u16* k_ws = (u16*)p;              p += plane;
    u16* v_ws = (u16*)p;              p += plane;
    const size_t need_split3 = (size_t)(p - (char*)d_ws);

    int use_split2 = (ws_size >= need_split2) ? 1 : 0;
    int use_split3 = (ws_size >= need_split3) ? 1 : 0;

    detect_mode<<<dim3(1), dim3(256), 0, stream>>>((const u16*)qkv_w, mode_flag);

    if (use_split2) {
        bias_gather3<<<dim3(NWIN * NHEADS), dim3(256), 0, stream>>>(
            bias_table, pos_index, bias_f, mode_flag);
        wconv<<<dim3(192), dim3(256), 0, stream>>>(
            qkv_w, qkv_b, proj_w, proj_b, qkvw_c, projw_c, qkvb_c, projb_c, mode_flag);
    }

    if (use_split3) {
        qkv_gemm<<<dim3(NBLK), dim3(576), 0, stream>>>(
            x, qkvw_c, qkvb_c, q_ws, k_ws, v_ws, mode_flag);
        attn_bh<<<dim3(NBLK * NHEADS), dim3(512), 0, stream>>>(
            q_ws, k_ws, v_ws, bias_f, o_ws);
        proj_gemm<<<dim3(NBLK * 9 / 8), dim3(512), 0, stream>>>(
            o_ws, projw_c, projb_c, d_out, mode_flag);
    } else if (use_split2) {
        attn_qkv<<<dim3(NBLK), dim3(576), 0, stream>>>(
            x, qkvw_c, qkvb_c, bias_f, o_ws, mode_flag);
        proj_gemm<<<dim3(NBLK * 9 / 8), dim3(512), 0, stream>>>(
            o_ws, projw_c, projb_c, d_out, mode_flag);
    } else {
        earth_attn_fused<<<dim3(NBLK), dim3(576), 0, stream>>>(
            x, qkv_w, qkv_b, proj_w, proj_b, bias_table, pos_index, d_out, mode_flag);
    }
}